// Round 6
// baseline (17366.174 us; speedup 1.0000x reference)
//
#include <hip/hip_runtime.h>
#include <stdint.h>

#define S_LEN 8192
#define E_DIM 100
#define H_DIM 768
#define NTAG 7
#define G4 3072            // 4*H
#define NBLK 96            // blocks per direction
#define NCHUNK 128
#define POLL_LIMIT 150000

typedef unsigned short u16;
typedef unsigned long long u64;
typedef __attribute__((ext_vector_type(4))) float f4v;
typedef __attribute__((ext_vector_type(2))) float f2v;

// input dtype flag (written by detect every call)
__device__ int g_isbf16;

__device__ __forceinline__ u16 f2bf(float f) {
    union { float f; unsigned u; } v; v.f = f;
    unsigned b = v.u;
    unsigned r = (b + 0x7FFFu + ((b >> 16) & 1u)) >> 16;   // RN
    return (u16)r;
}
__device__ __forceinline__ float bf2f(u16 u) {
    union { unsigned u; float f; } v; v.u = ((unsigned)u) << 16;
    return v.f;
}
__device__ __forceinline__ float getv(const void* p, size_t i, int isbf) {
    return isbf ? bf2f(((const u16*)p)[i]) : ((const float*)p)[i];
}
// fast transcendentals on the serial gate chain: v_exp + v_rcp.
__device__ __forceinline__ float sigm(float x) {
    return __builtin_amdgcn_rcpf(1.0f + __expf(-x));
}
__device__ __forceinline__ float ftanh(float x) {
    return 2.0f * __builtin_amdgcn_rcpf(1.0f + __expf(-2.0f * x)) - 1.0f;
}

// ---------------------------------------------------------------------------
// Dtype probe (256 B read, safe under either dtype).
// ---------------------------------------------------------------------------
__global__ void detect(const void* x) {
    __shared__ int cnt;
    if (threadIdx.x == 0) cnt = 0;
    __syncthreads();
    unsigned v = ((const u16*)x)[2 * threadIdx.x];
    int e = (v >> 7) & 0xFF;
    if (e >= 110 && e <= 132) atomicAdd(&cnt, 1);
    __syncthreads();
    if (threadIdx.x == 0) g_isbf16 = (cnt >= 100) ? 1 : 0;
}

// ---------------------------------------------------------------------------
// Prep: fold biases, seed c0, seed self-tagged h slots.
// slots layout: [dir][buf][384] u64 = (tag<<32) | (bf16 pair).
// Slot s holds units (2s, 2s+1) — matches pubslot = blk*4+wave publishing
// units (blk*8+2w, +1), since 2*(4*blk+w) = 8*blk+2w.
// ---------------------------------------------------------------------------
__global__ void prep(const void* bihf, const void* bhhf,
                     const void* bihb, const void* bhhb,
                     const void* h0, const void* c0,
                     float* __restrict__ cst, float* __restrict__ bias,
                     u64* __restrict__ slots) {
    const int isbf = g_isbf16;
    int i = blockIdx.x * blockDim.x + threadIdx.x;   // 0..3071
    if (i < G4) {
        bias[i]      = getv(bihf, i, isbf) + getv(bhhf, i, isbf);
        bias[G4 + i] = getv(bihb, i, isbf) + getv(bhhb, i, isbf);
    }
    if (i < 2 * H_DIM) cst[i] = getv(c0, i, isbf);
    if (i < 384) {
        unsigned pf = (unsigned)f2bf(getv(h0, 2 * i, isbf))
                    | ((unsigned)f2bf(getv(h0, 2 * i + 1, isbf)) << 16);
        unsigned pb = (unsigned)f2bf(getv(h0, H_DIM + 2 * i, isbf))
                    | ((unsigned)f2bf(getv(h0, H_DIM + 2 * i + 1, isbf)) << 16);
        slots[i]        = (u64)pf;                    // fwd buf0, tag 0
        slots[768 + i]  = (u64)pb;                    // bwd buf0, tag 0
        slots[384 + i]  = 0xFFFFFFFF00000000ull;      // fwd buf1, invalid tag
        slots[1152 + i] = 0xFFFFFFFF00000000ull;      // bwd buf1, invalid tag
    }
}

// staggered-poll asm helpers (R5-verified). Poll loads MUST carry sc0 sc1
// (coherent-scope read, same point __hip_atomic_load(AGENT) uses).
#define PISSUE(A, B)                                                     \
    asm volatile("global_load_dwordx2 %0, %2, off sc0 sc1\n\t"           \
                 "global_load_dwordx2 %1, %3, off sc0 sc1"               \
                 : "=&v"(A), "=&v"(B) : "v"(pa), "v"(pb) : "memory")
#define PWAIT2(A, B)                                                     \
    asm volatile("s_waitcnt vmcnt(2)" : "+v"(A), "+v"(B))
#define PDRAIN4(A, B, C, D)                                              \
    asm volatile("s_waitcnt vmcnt(0)"                                    \
                 : "+v"(A), "+v"(B), "+v"(C), "+v"(D))

// ---------------------------------------------------------------------------
// Persistent bidirectional LSTM. 192 blocks (96/dir), 256 thr. NEW compute
// decomposition (R6): thread t = (unit uloc=t>>5, col-slice j=t&31); each
// lane owns ALL 4 gate rows of ONE unit x a 24-col slice of h (96 weight
// regs, unchanged) + a 4-col slice of x (lanes j<25). LDS h-reads drop 4x
// (24 floats/lane, 12 conflict-free ds_read_b64 at padded stride 26; lanes
// j and j+32 broadcast). The 32-lane shfl_xor reduce leaves every lane
// holding all 4 gate sums of its unit -> gate broadcasts eliminated; gates
// computed redundantly per lane (cheap VALU). Publish/poll/slots/barrier
// topology identical to R5 (verified).
// ---------------------------------------------------------------------------
__global__ __launch_bounds__(256, 1) void lstm_persist(
        const void* x,
        const void* wihf, const void* whhf,
        const void* wihb, const void* whhb,
        u16* __restrict__ hfseq, u16* __restrict__ hbseq,
        float* __restrict__ cstate, const float* __restrict__ biasv,
        u64* __restrict__ slots, int* __restrict__ bail) {
    const int isbf = g_isbf16;
    const int bid = blockIdx.x;
    const int dir = (bid >= NBLK) ? 1 : 0;
    const int blk = bid - dir * NBLK;
    const int tid = threadIdx.x;
    const int wave = tid >> 6, lane = tid & 63;
    const int half = (tid >> 5) & 1;
    const int jj = tid & 31;               // column-slice index
    const int uloc = wave * 2 + half;      // 0..7
    const int u = blk * 8 + uloc;          // this lane's hidden unit
    u16* hseq = dir ? hbseq : hfseq;
    u64* myslots = slots + (size_t)dir * 768;
    const void* Wih = dir ? wihb : wihf;
    const void* Whh = dir ? whhb : whhf;

    __shared__ float sh[2 * 832];          // h_t fp32, (k/24)*26 + k%24

    // ---- preload weights: whh[g*24+c] = W_hh[g*768+u][jj*24+c] ----
    float whh[96], wih[16];
    #pragma unroll
    for (int i = 0; i < 16; ++i) wih[i] = 0.f;
    if (isbf) {
        #pragma unroll
        for (int g = 0; g < 4; ++g) {
            const unsigned* p = (const unsigned*)((const u16*)Whh
                              + (size_t)(g * H_DIM + u) * H_DIM + jj * 24);
            #pragma unroll
            for (int i = 0; i < 12; ++i) {
                unsigned q = p[i];
                whh[g * 24 + 2 * i]     = bf2f((u16)q);
                whh[g * 24 + 2 * i + 1] = bf2f((u16)(q >> 16));
            }
        }
        if (jj < 25) {
            #pragma unroll
            for (int g = 0; g < 4; ++g) {
                const unsigned* q = (const unsigned*)((const u16*)Wih
                                  + (size_t)(g * H_DIM + u) * E_DIM + 4 * jj);
                unsigned q0 = q[0], q1 = q[1];
                wih[g * 4 + 0] = bf2f((u16)q0);
                wih[g * 4 + 1] = bf2f((u16)(q0 >> 16));
                wih[g * 4 + 2] = bf2f((u16)q1);
                wih[g * 4 + 3] = bf2f((u16)(q1 >> 16));
            }
        }
    } else {
        #pragma unroll
        for (int g = 0; g < 4; ++g) {
            const float* p = (const float*)Whh
                           + (size_t)(g * H_DIM + u) * H_DIM + jj * 24;
            #pragma unroll
            for (int i = 0; i < 24; ++i) whh[g * 24 + i] = p[i];
        }
        if (jj < 25) {
            #pragma unroll
            for (int g = 0; g < 4; ++g) {
                const float* q = (const float*)Wih
                               + (size_t)(g * H_DIM + u) * E_DIM + 4 * jj;
                wih[g * 4 + 0] = q[0]; wih[g * 4 + 1] = q[1];
                wih[g * 4 + 2] = q[2]; wih[g * 4 + 3] = q[3];
            }
        }
    }
    float b0r = biasv[dir * G4 + 0 * H_DIM + u];
    float b1r = biasv[dir * G4 + 1 * H_DIM + u];
    float b2r = biasv[dir * G4 + 2 * H_DIM + u];
    float b3r = biasv[dir * G4 + 3 * H_DIM + u];
    float cst = cstate[dir * H_DIM + u];

    // ---- chunked slot assignment (R5): wave w polls slots [96w, 96w+96) ----
    const int sA = wave * 96 + lane;
    const int sB = (lane < 32) ? (wave * 96 + 64 + lane) : sA;
    const int kA = 2 * sA, kB = 2 * sB;                   // h index of payload
    const int oA = (kA / 24) * 26 + kA % 24;              // LDS offsets (new)
    const int oB = (kB / 24) * 26 + kB % 24;
    const int pubslot = blk * 4 + wave;

    // ---- x-slice register pipeline: lane jj<25 owns x cols 4jj..4jj+3 ----
    float    xf[4];
    unsigned xu[2];
    auto load_x = [&](int t) {
        const int sx = dir ? (S_LEN - 1 - t) : t;
        if (jj < 25) {                      // guard: 4*jj+3 <= 99 only if jj<25
            if (isbf) {
                const unsigned* p = (const unsigned*)((const u16*)x
                                  + (size_t)sx * E_DIM + 4 * jj);
                xu[0] = p[0]; xu[1] = p[1];
            } else {
                f4v v = *(const f4v*)((const float*)x + (size_t)sx * E_DIM + 4 * jj);
                xf[0] = v.x; xf[1] = v.y; xf[2] = v.z; xf[3] = v.w;
            }
        }
    };

    load_x(0);   // prologue

    for (int t = 0; t < S_LEN; ++t) {
        // ---- x partial products into the 4 gate accumulators ----
        float a0 = 0.f, a1 = 0.f, a2 = 0.f, a3 = 0.f;
        if (jj < 25) {
            float x0, x1, x2, x3;
            if (isbf) {
                x0 = bf2f((u16)xu[0]); x1 = bf2f((u16)(xu[0] >> 16));
                x2 = bf2f((u16)xu[1]); x3 = bf2f((u16)(xu[1] >> 16));
            } else {
                x0 = xf[0]; x1 = xf[1]; x2 = xf[2]; x3 = xf[3];
            }
            a0 = wih[0]  * x0 + wih[1]  * x1 + wih[2]  * x2 + wih[3]  * x3;
            a1 = wih[4]  * x0 + wih[5]  * x1 + wih[6]  * x2 + wih[7]  * x3;
            a2 = wih[8]  * x0 + wih[9]  * x1 + wih[10] * x2 + wih[11] * x3;
            a3 = wih[12] * x0 + wih[13] * x1 + wih[14] * x2 + wih[15] * x3;
        }

        // ---- staggered 2-deep poll of self-tagged h_t slots (R5) ----
        u64 va = 0, vb = 0;
        {
            const u64* buf = myslots + (size_t)(t & 1) * 384;
            const u64* pa = buf + sA;
            const u64* pb = buf + sB;
            const unsigned tgt = (unsigned)t;
            u64 a0p, b0p, a1p, b1p;
            int polls = 0;
            bool found = false;
            asm volatile("s_waitcnt vmcnt(0)" ::: "memory");
            for (;;) {
                PISSUE(a0p, b0p);
                for (int it = 0; it < 32; ++it) {
                    PISSUE(a1p, b1p);
                    PWAIT2(a0p, b0p);
                    if (__all(((unsigned)(a0p >> 32) == tgt) &
                              ((unsigned)(b0p >> 32) == tgt))) {
                        va = a0p; vb = b0p; found = true; break;
                    }
                    PISSUE(a0p, b0p);
                    PWAIT2(a1p, b1p);
                    if (__all(((unsigned)(a1p >> 32) == tgt) &
                              ((unsigned)(b1p >> 32) == tgt))) {
                        va = a1p; vb = b1p; found = true; break;
                    }
                }
                PDRAIN4(a0p, b0p, a1p, b1p);
                if (found) break;
                u64 f0 = __hip_atomic_load(&buf[sA], __ATOMIC_RELAXED,
                                           __HIP_MEMORY_SCOPE_AGENT);
                u64 f1 = __hip_atomic_load(&buf[sB], __ATOMIC_RELAXED,
                                           __HIP_MEMORY_SCOPE_AGENT);
                if (__all(((unsigned)(f0 >> 32) == tgt) &
                          ((unsigned)(f1 >> 32) == tgt))) {
                    va = f0; vb = f1; break;
                }
                polls += 64;
                if (__hip_atomic_load(bail, __ATOMIC_RELAXED,
                                      __HIP_MEMORY_SCOPE_AGENT)) {
                    va = f0; vb = f1; break;
                }
                if (polls > POLL_LIMIT) {
                    __hip_atomic_store(bail, 1, __ATOMIC_RELAXED,
                                       __HIP_MEMORY_SCOPE_AGENT);
                    va = f0; vb = f1; break;
                }
                __builtin_amdgcn_s_sleep(2);
            }

            // ---- unpack payload -> LDS (double-buffered, new layout) ----
            float* shb = sh + (t & 1) * 832;
            unsigned p0 = (unsigned)va;
            shb[oA]     = bf2f((u16)p0);
            shb[oA + 1] = bf2f((u16)(p0 >> 16));
            if (lane < 32) {
                unsigned p1 = (unsigned)vb;
                shb[oB]     = bf2f((u16)p1);
                shb[oB + 1] = bf2f((u16)(p1 >> 16));
            }
        }
        __syncthreads();   // single barrier/step: staging visible block-wide

        // ---- issue x loads for t+1 (latency hidden under h-proj) ----
        load_x((t + 1 < S_LEN) ? (t + 1) : t);

        // ---- h-projection: 24 cols x 4 gates = 96 FMA from 12 f2v reads ----
        const f2v* h2 = (const f2v*)(sh + (t & 1) * 832 + jj * 26);
        #pragma unroll
        for (int i = 0; i < 12; ++i) {
            f2v hv = h2[i];
            a0 += whh[2 * i]      * hv.x + whh[2 * i + 1]      * hv.y;
            a1 += whh[24 + 2 * i] * hv.x + whh[24 + 2 * i + 1] * hv.y;
            a2 += whh[48 + 2 * i] * hv.x + whh[48 + 2 * i + 1] * hv.y;
            a3 += whh[72 + 2 * i] * hv.x + whh[72 + 2 * i + 1] * hv.y;
        }

        // ---- 32-lane reduce: all 4 gate sums land in every lane ----
        #pragma unroll
        for (int m = 1; m <= 16; m <<= 1) {
            a0 += __shfl_xor(a0, m);
            a1 += __shfl_xor(a1, m);
            a2 += __shfl_xor(a2, m);
            a3 += __shfl_xor(a3, m);
        }

        // ---- gates (computed redundantly in all 32 lanes of the unit) ----
        float ii = sigm(a0 + b0r), ff = sigm(a1 + b1r);
        float gt = ftanh(a2 + b2r), oo = sigm(a3 + b3r);
        float c = ff * cst + ii * gt;
        cst = c;
        float h = oo * ftanh(c);

        // ---- publish: tag+payload in ONE 64-bit relaxed agent atomic,
        //      per-wave IMMEDIATE (no extra barrier). Mirror: write-through.
        {
            float hodd = __shfl(h, 32);                  // lane0 <- lane32's unit
            if (lane == 0) {
                unsigned pk = (unsigned)f2bf(h) | ((unsigned)f2bf(hodd) << 16);
                u64 sv = (((u64)(unsigned)(t + 1)) << 32) | (u64)pk;
                __hip_atomic_store(&myslots[(size_t)((t + 1) & 1) * 384 + pubslot],
                                   sv, __ATOMIC_RELAXED, __HIP_MEMORY_SCOPE_AGENT);
                __hip_atomic_store(
                    &((unsigned*)(hseq + (size_t)(t + 1) * H_DIM))[pubslot],
                    pk, __ATOMIC_RELAXED, __HIP_MEMORY_SCOPE_AGENT);
            }
        }
        // no trailing barrier: next step stages into the other LDS buffer,
        // and all reads of this buffer completed before the barrier above.
    }
}

// ---------------------------------------------------------------------------
// feats[s][j] = [hf[s], hb[s]] . w_tag[j] + b_tag[j]; one wave per s.
// ---------------------------------------------------------------------------
__global__ __launch_bounds__(256) void feats_kernel(const u16* __restrict__ hfseq,
                                                    const u16* __restrict__ hbseq,
                                                    const void* w_tag, const void* b_tag,
                                                    float* __restrict__ feats) {
    const int isbf = g_isbf16;
    const int wave = threadIdx.x >> 6, lane = threadIdx.x & 63;
    const int s = blockIdx.x * 4 + wave;
    if (s >= S_LEN) return;
    const u16* hf = hfseq + (size_t)(s + 1) * H_DIM;
    const u16* hb = hbseq + (size_t)(S_LEN - s) * H_DIM;
    float hv[12], hbv[12];
    #pragma unroll
    for (int i = 0; i < 12; ++i) {
        hv[i]  = bf2f(hf[lane + 64 * i]);
        hbv[i] = bf2f(hb[lane + 64 * i]);
    }
    float myf = 0.f;
    for (int j = 0; j < NTAG; ++j) {
        const size_t wr = (size_t)j * (2 * H_DIM);
        float d = 0.f;
        #pragma unroll
        for (int i = 0; i < 12; ++i)
            d += hv[i] * getv(w_tag, wr + lane + 64 * i, isbf)
               + hbv[i] * getv(w_tag, wr + H_DIM + lane + 64 * i, isbf);
        #pragma unroll
        for (int m = 1; m < 64; m <<= 1) d += __shfl_xor(d, m);
        if (lane == j) myf = d + getv(b_tag, j, isbf);
    }
    if (lane < NTAG) feats[(size_t)s * NTAG + lane] = myf;
}

// ---------------------------------------------------------------------------
// CRF parallel scan (log-semiring 7x7 product is associative).
// ---------------------------------------------------------------------------
__global__ void crf_chunks(const void* trans,
                           const float* __restrict__ feats,
                           float* __restrict__ cmats) {
    const int isbf = g_isbf16;
    const int c = blockIdx.x;
    const int lane = threadIdx.x;
    const bool act = lane < 49;
    const int i = act ? (lane / 7) : 0;
    const int j = lane % 7;
    float tc[7];
    #pragma unroll
    for (int k = 0; k < 7; ++k) tc[k] = getv(trans, k * 7 + j, isbf);
    float R = (act && (lane / 7) == j) ? 0.f : -1e30f;
    int s0 = 1 + c * 64;
    int s1 = s0 + 64; if (s1 > S_LEN) s1 = S_LEN;
    for (int t = s0; t < s1; ++t) {
        float fj = feats[t * NTAG + j];
        float r[7];
        #pragma unroll
        for (int k = 0; k < 7; ++k) r[k] = __shfl(R, i * 7 + k) + tc[k];
        float m = r[0];
        #pragma unroll
        for (int k = 1; k < 7; ++k) m = fmaxf(m, r[k]);
        float sum = 0.f;
        #pragma unroll
        for (int k = 0; k < 7; ++k) sum += __expf(r[k] - m);
        R = m + __logf(sum) + fj;
    }
    if (act) cmats[c * 49 + lane] = R;
}

__global__ void crf_final(const void* start_t, const void* end_t,
                          const float* __restrict__ feats,
                          const float* __restrict__ cmats,
                          void* __restrict__ out) {
    const int isbf = g_isbf16;
    const int lane = threadIdx.x;
    const int j = (lane < 7) ? lane : 0;
    float alpha = (lane < 7) ? (getv(start_t, lane, isbf) + feats[lane]) : -1e30f;
    for (int c = 0; c < NCHUNK; ++c) {
        float r[7];
        #pragma unroll
        for (int i = 0; i < 7; ++i)
            r[i] = __shfl(alpha, i) + cmats[c * 49 + i * 7 + j];
        float m = r[0];
        #pragma unroll
        for (int i = 1; i < 7; ++i) m = fmaxf(m, r[i]);
        float sum = 0.f;
        #pragma unroll
        for (int i = 0; i < 7; ++i) sum += __expf(r[i] - m);
        float na = m + __logf(sum);
        alpha = (lane < 7) ? na : -1e30f;
    }
    float v = (lane < 7) ? (alpha + getv(end_t, lane, isbf)) : -1e30f;
    float m = v;
    #pragma unroll
    for (int d = 1; d < 8; d <<= 1) m = fmaxf(m, __shfl_xor(m, d));
    float s = __expf(v - m);
    #pragma unroll
    for (int d = 1; d < 8; d <<= 1) s += __shfl_xor(s, d);
    if (lane == 0) {
        float r = m + __logf(s);
        if (isbf) ((u16*)out)[0] = f2bf(r);
        else      ((float*)out)[0] = r;
    }
}

// ---------------------------------------------------------------------------
extern "C" void kernel_launch(void* const* d_in, const int* in_sizes, int n_in,
                              void* d_out, int out_size, void* d_ws, size_t ws_size,
                              hipStream_t stream) {
    const void* sentence = d_in[0];      // (8192, 1, 100)
    const void* w_ih_f   = d_in[1];      // (3072, 100)
    const void* w_hh_f   = d_in[2];      // (3072, 768)
    const void* b_ih_f   = d_in[3];
    const void* b_hh_f   = d_in[4];
    const void* w_ih_b   = d_in[5];
    const void* w_hh_b   = d_in[6];
    const void* b_ih_b   = d_in[7];
    const void* b_hh_b   = d_in[8];
    const void* h0       = d_in[9];      // (2,1,768)
    const void* c0       = d_in[10];
    const void* w_tag    = d_in[11];     // (7, 1536)
    const void* b_tag    = d_in[12];
    const void* trans    = d_in[13];
    const void* start_t  = d_in[14];
    const void* end_t    = d_in[15];
    (void)in_sizes; (void)n_in; (void)out_size; (void)ws_size;

    // ---- d_ws scratch: ~25.3 MB, fully rewritten each call ----
    char* ws = (char*)d_ws;
    size_t o = 0;
    auto take = [&](size_t bytes) -> char* {
        char* p = ws + o;
        o += (bytes + 255) & ~(size_t)255;
        return p;
    };
    u16*   hfseq  = (u16*)take((size_t)(S_LEN + 1) * H_DIM * 2);
    u16*   hbseq  = (u16*)take((size_t)(S_LEN + 1) * H_DIM * 2);
    float* cstate = (float*)take((size_t)2 * H_DIM * 4);
    float* biasv  = (float*)take((size_t)2 * G4 * 4);
    float* featsb = (float*)take((size_t)S_LEN * NTAG * 4);
    float* cmats  = (float*)take((size_t)NCHUNK * 49 * 4);
    u64*   slots  = (u64*)take((size_t)2 * 2 * 384 * 8);   // [dir][buf][384]
    int*   bail   = (int*)take((size_t)256 * 4);

    detect<<<1, 128, 0, stream>>>(sentence);
    prep<<<12, 256, 0, stream>>>(b_ih_f, b_hh_f, b_ih_b, b_hh_b, h0, c0,
                                 cstate, biasv, slots);
    (void)hipMemsetAsync(bail, 0, 4, stream);

    lstm_persist<<<2 * NBLK, 256, 0, stream>>>(sentence,
                                               w_ih_f, w_hh_f, w_ih_b, w_hh_b,
                                               hfseq, hbseq, cstate, biasv,
                                               slots, bail);

    feats_kernel<<<S_LEN / 4, 256, 0, stream>>>(hfseq, hbseq, w_tag, b_tag, featsb);
    crf_chunks<<<NCHUNK, 64, 0, stream>>>(trans, featsb, cmats);
    crf_final<<<1, 64, 0, stream>>>(start_t, end_t, featsb, cmats, d_out);
}

// Round 7
// 16002.765 us; speedup vs baseline: 1.0852x; 1.0852x over previous
//
#include <hip/hip_runtime.h>
#include <stdint.h>

#define S_LEN 8192
#define E_DIM 100
#define H_DIM 768
#define NTAG 7
#define G4 3072            // 4*H
#define NBLK 96            // blocks per direction
#define NCHUNK 128
#define POLL_LIMIT 150000

typedef unsigned short u16;
typedef unsigned long long u64;
typedef __attribute__((ext_vector_type(4))) float f4v;
typedef __attribute__((ext_vector_type(4))) unsigned u4v;

// input dtype flag (written by detect every call)
__device__ int g_isbf16;

__device__ __forceinline__ u16 f2bf(float f) {
    union { float f; unsigned u; } v; v.f = f;
    unsigned b = v.u;
    unsigned r = (b + 0x7FFFu + ((b >> 16) & 1u)) >> 16;   // RN
    return (u16)r;
}
__device__ __forceinline__ float bf2f(u16 u) {
    union { unsigned u; float f; } v; v.u = ((unsigned)u) << 16;
    return v.f;
}
// packed-u32 bf16 unpack (reinterpret, no rounding):
__device__ __forceinline__ float bl(unsigned q) {   // low u16 -> float
    union { unsigned u; float f; } v; v.u = q << 16; return v.f;
}
__device__ __forceinline__ float bh(unsigned q) {   // high u16 -> float
    union { unsigned u; float f; } v; v.u = q & 0xFFFF0000u; return v.f;
}
__device__ __forceinline__ float getv(const void* p, size_t i, int isbf) {
    return isbf ? bf2f(((const u16*)p)[i]) : ((const float*)p)[i];
}
// fast transcendentals on the serial gate chain: v_exp + v_rcp.
__device__ __forceinline__ float sigm(float x) {
    return __builtin_amdgcn_rcpf(1.0f + __expf(-x));
}
__device__ __forceinline__ float ftanh(float x) {
    return 2.0f * __builtin_amdgcn_rcpf(1.0f + __expf(-2.0f * x)) - 1.0f;
}

// ---------------------------------------------------------------------------
// Dtype probe (256 B read, safe under either dtype).
// ---------------------------------------------------------------------------
__global__ void detect(const void* x) {
    __shared__ int cnt;
    if (threadIdx.x == 0) cnt = 0;
    __syncthreads();
    unsigned v = ((const u16*)x)[2 * threadIdx.x];
    int e = (v >> 7) & 0xFF;
    if (e >= 110 && e <= 132) atomicAdd(&cnt, 1);
    __syncthreads();
    if (threadIdx.x == 0) g_isbf16 = (cnt >= 100) ? 1 : 0;
}

// ---------------------------------------------------------------------------
// Prep: fold biases, seed c0, seed self-tagged h slots.
// slots layout: [dir][buf][384] u64 = (tag<<32) | (bf16 pair).
//   buf0 seeded with tag 0 + h0 payload; buf1 seeded with invalid tag
//   (kills stale tags from a previous invocation of this workspace).
// ---------------------------------------------------------------------------
__global__ void prep(const void* bihf, const void* bhhf,
                     const void* bihb, const void* bhhb,
                     const void* h0, const void* c0,
                     float* __restrict__ cst, float* __restrict__ bias,
                     u64* __restrict__ slots) {
    const int isbf = g_isbf16;
    int i = blockIdx.x * blockDim.x + threadIdx.x;   // 0..3071
    if (i < G4) {
        bias[i]      = getv(bihf, i, isbf) + getv(bhhf, i, isbf);
        bias[G4 + i] = getv(bihb, i, isbf) + getv(bhhb, i, isbf);
    }
    if (i < 2 * H_DIM) cst[i] = getv(c0, i, isbf);
    if (i < 384) {
        unsigned pf = (unsigned)f2bf(getv(h0, 2 * i, isbf))
                    | ((unsigned)f2bf(getv(h0, 2 * i + 1, isbf)) << 16);
        unsigned pb = (unsigned)f2bf(getv(h0, H_DIM + 2 * i, isbf))
                    | ((unsigned)f2bf(getv(h0, H_DIM + 2 * i + 1, isbf)) << 16);
        slots[i]        = (u64)pf;                    // fwd buf0, tag 0
        slots[768 + i]  = (u64)pb;                    // bwd buf0, tag 0
        slots[384 + i]  = 0xFFFFFFFF00000000ull;      // fwd buf1, invalid tag
        slots[1152 + i] = 0xFFFFFFFF00000000ull;      // bwd buf1, invalid tag
    }
}

// staggered-poll asm helpers (R5-verified). Poll loads MUST carry sc0 sc1
// (coherent-scope read, same point __hip_atomic_load(AGENT) uses).
#define PISSUE(A, B)                                                     \
    asm volatile("global_load_dwordx2 %0, %2, off sc0 sc1\n\t"           \
                 "global_load_dwordx2 %1, %3, off sc0 sc1"               \
                 : "=&v"(A), "=&v"(B) : "v"(pa), "v"(pb) : "memory")
#define PWAIT2(A, B)                                                     \
    asm volatile("s_waitcnt vmcnt(2)" : "+v"(A), "+v"(B))
#define PDRAIN4(A, B, C, D)                                              \
    asm volatile("s_waitcnt vmcnt(0)"                                    \
                 : "+v"(A), "+v"(B), "+v"(C), "+v"(D))

// ---------------------------------------------------------------------------
// Persistent bidirectional LSTM. 192 blocks (96/dir), 256 thr: 32 gate rows
// x 8 col-segments (R5 decomposition, verified best). Cross-block h exchange
// via SELF-TAGGED 64-bit slots; staggered 2-deep coherent poll; per-wave
// immediate publish; ONE barrier per step. R7 change: LDS h staging is
// PACKED bf16 u32 (payload stored raw) -> 1 ds_write_b32 per slot (was 2
// f32 writes) and 12 ds_read_b128 per thread (was 24); unpack via 2 cheap
// VALU reinterprets per u32 on the per-SIMD VALU pipes. Layout stride 52
// u32/seg: segs hit bank groups {0,20,8,28,16,4,24,12}(+0..3) = all 32
// banks exactly once; same-seg rows broadcast -> conflict-free.
// ---------------------------------------------------------------------------
__global__ __launch_bounds__(256, 1) void lstm_persist(
        const void* x,
        const void* wihf, const void* whhf,
        const void* wihb, const void* whhb,
        u16* __restrict__ hfseq, u16* __restrict__ hbseq,
        float* __restrict__ cstate, const float* __restrict__ biasv,
        u64* __restrict__ slots, int* __restrict__ bail) {
    const int isbf = g_isbf16;
    const int bid = blockIdx.x;
    const int dir = (bid >= NBLK) ? 1 : 0;
    const int blk = bid - dir * NBLK;
    const int tid = threadIdx.x;
    const int wave = tid >> 6, lane = tid & 63;
    const int seg = tid & 7;            // col segment
    const int row = tid >> 3;           // 0..31 local gate rows
    const int gamma = row & 3;          // gate: 0=i 1=f 2=g 3=o
    const int uloc = row >> 2;          // 0..7
    const int u = blk * 8 + uloc;
    const size_t grow = (size_t)(gamma * H_DIM + u);       // row in (3072, .)
    u16* hseq = dir ? hbseq : hfseq;
    u64* myslots = slots + (size_t)dir * 768;
    const void* Wih = dir ? wihb : wihf;
    const void* Whh = dir ? whhb : whhf;

    __shared__ unsigned shp[2 * 416];   // 2 x (8 segs x 52): packed bf16 pairs

    // ---- preload weights into registers (one-time) ----
    float whh[96], wih[13];
    if (isbf) {
        const unsigned* p = (const unsigned*)((const u16*)Whh + grow * H_DIM + seg * 96);
        #pragma unroll
        for (int i = 0; i < 48; ++i) {
            unsigned q = p[i];
            whh[2 * i] = bf2f((u16)q); whh[2 * i + 1] = bf2f((u16)(q >> 16));
        }
        const unsigned* px = (const unsigned*)((const u16*)Wih + grow * E_DIM + seg * 12);
        #pragma unroll
        for (int i = 0; i < 6; ++i) {
            unsigned q = px[i];
            wih[2 * i] = bf2f((u16)q); wih[2 * i + 1] = bf2f((u16)(q >> 16));
        }
        wih[12] = (seg < 4) ? bf2f(((const u16*)Wih)[grow * E_DIM + 96 + seg]) : 0.f;
    } else {
        const float* p = (const float*)Whh + grow * H_DIM + seg * 96;
        #pragma unroll
        for (int i = 0; i < 96; ++i) whh[i] = p[i];
        const float* px = (const float*)Wih + grow * E_DIM + seg * 12;
        #pragma unroll
        for (int i = 0; i < 12; ++i) wih[i] = px[i];
        wih[12] = (seg < 4) ? ((const float*)Wih)[grow * E_DIM + 96 + seg] : 0.f;
    }
    const float bias_r = biasv[dir * G4 + grow];
    const int uhalf = blk * 8 + wave * 2 + (lane >> 5);    // unit of this half-wave
    float cst = cstate[dir * H_DIM + uhalf];

    // ---- chunked slot assignment (R5): wave w polls slots [96w, 96w+96) ----
    const int sA = wave * 96 + lane;
    const int sB = (lane < 32) ? (wave * 96 + 64 + lane) : sA;
    // packed LDS staging positions: u32 index s -> (s/48)*52 + s%48
    const int pA = (sA / 48) * 52 + sA % 48;
    const int pB = (sB / 48) * 52 + sB % 48;
    const int pubslot = blk * 4 + wave;     // slot this wave publishes

    // ---- x-row register pipeline ----
    float    xf[13];        // fp32 path
    unsigned xu[6];         // bf16 path (96 cols)
    u16      xt16 = 0;      // bf16 tail col
    auto load_x = [&](int t) {
        const int sx = dir ? (S_LEN - 1 - t) : t;
        if (isbf) {
            const unsigned* xr = (const unsigned*)((const u16*)x + (size_t)sx * E_DIM + seg * 12);
            #pragma unroll
            for (int i = 0; i < 6; ++i) xu[i] = xr[i];
            if (seg < 4) xt16 = ((const u16*)x)[(size_t)sx * E_DIM + 96 + seg];
        } else {
            const float* xr = (const float*)x + (size_t)sx * E_DIM + seg * 12;
            #pragma unroll
            for (int i = 0; i < 12; ++i) xf[i] = xr[i];
            xf[12] = (seg < 4) ? ((const float*)x)[(size_t)sx * E_DIM + 96 + seg] : 0.f;
        }
    };
    auto fma_x = [&]() -> float {
        float ax = 0.f;
        if (isbf) {
            #pragma unroll
            for (int i = 0; i < 6; ++i) {
                unsigned q = xu[i];
                ax += wih[2 * i] * bf2f((u16)q) + wih[2 * i + 1] * bf2f((u16)(q >> 16));
            }
            if (seg < 4) ax += wih[12] * bf2f(xt16);
        } else {
            #pragma unroll
            for (int i = 0; i < 12; ++i) ax += wih[i] * xf[i];
            ax += wih[12] * xf[12];     // xf[12]=0 when seg>=4
        }
        return ax;
    };

    load_x(0);   // prologue

    for (int t = 0; t < S_LEN; ++t) {
        // ---- x-projection: pure FMAs on prefetched registers ----
        float ax = fma_x();

        // ---- staggered 2-deep poll of self-tagged h_t slots (R5) ----
        u64 va = 0, vb = 0;
        {
            const u64* buf = myslots + (size_t)(t & 1) * 384;
            const u64* pa = buf + sA;
            const u64* pb = buf + sB;
            const unsigned tgt = (unsigned)t;
            u64 a0p, b0p, a1p, b1p;
            int polls = 0;
            bool found = false;
            asm volatile("s_waitcnt vmcnt(0)" ::: "memory");
            for (;;) {
                PISSUE(a0p, b0p);
                for (int it = 0; it < 32; ++it) {
                    PISSUE(a1p, b1p);
                    PWAIT2(a0p, b0p);
                    if (__all(((unsigned)(a0p >> 32) == tgt) &
                              ((unsigned)(b0p >> 32) == tgt))) {
                        va = a0p; vb = b0p; found = true; break;
                    }
                    PISSUE(a0p, b0p);
                    PWAIT2(a1p, b1p);
                    if (__all(((unsigned)(a1p >> 32) == tgt) &
                              ((unsigned)(b1p >> 32) == tgt))) {
                        va = a1p; vb = b1p; found = true; break;
                    }
                }
                PDRAIN4(a0p, b0p, a1p, b1p);
                if (found) break;
                u64 f0 = __hip_atomic_load(&buf[sA], __ATOMIC_RELAXED,
                                           __HIP_MEMORY_SCOPE_AGENT);
                u64 f1 = __hip_atomic_load(&buf[sB], __ATOMIC_RELAXED,
                                           __HIP_MEMORY_SCOPE_AGENT);
                if (__all(((unsigned)(f0 >> 32) == tgt) &
                          ((unsigned)(f1 >> 32) == tgt))) {
                    va = f0; vb = f1; break;
                }
                polls += 64;
                if (__hip_atomic_load(bail, __ATOMIC_RELAXED,
                                      __HIP_MEMORY_SCOPE_AGENT)) {
                    va = f0; vb = f1; break;
                }
                if (polls > POLL_LIMIT) {
                    __hip_atomic_store(bail, 1, __ATOMIC_RELAXED,
                                       __HIP_MEMORY_SCOPE_AGENT);
                    va = f0; vb = f1; break;
                }
                __builtin_amdgcn_s_sleep(2);
            }

            // ---- stage RAW packed payload -> LDS (1 ds_write_b32/slot) ----
            unsigned* shb = shp + (t & 1) * 416;
            shb[pA] = (unsigned)va;
            if (lane < 32) shb[pB] = (unsigned)vb;
        }
        __syncthreads();   // single barrier/step: staging visible block-wide

        // ---- issue x-row loads for t+1 (latency hidden under h-proj) ----
        load_x((t + 1 < S_LEN) ? (t + 1) : t);

        // ---- h-projection: 96 FMA from 12 ds_read_b128 (packed bf16) ----
        const u4v* h4 = (const u4v*)(shp + (t & 1) * 416 + seg * 52);
        float a0 = 0.f, a1 = 0.f, a2 = 0.f, a3 = 0.f;
        #pragma unroll
        for (int i = 0; i < 12; ++i) {
            u4v q = h4[i];
            a0 += whh[8 * i]     * bl(q.x);
            a1 += whh[8 * i + 1] * bh(q.x);
            a2 += whh[8 * i + 2] * bl(q.y);
            a3 += whh[8 * i + 3] * bh(q.y);
            a0 += whh[8 * i + 4] * bl(q.z);
            a1 += whh[8 * i + 5] * bh(q.z);
            a2 += whh[8 * i + 6] * bl(q.w);
            a3 += whh[8 * i + 7] * bh(q.w);
        }
        float acc = ax + (a0 + a1) + (a2 + a3);
        acc += __shfl_xor(acc, 1);
        acc += __shfl_xor(acc, 2);
        acc += __shfl_xor(acc, 4);       // 8-lane row sum
        float g = acc + bias_r;

        const int base = lane & 32;      // 4 gates of this half-wave's unit
        float gi = __shfl(g, base + 0);
        float gf = __shfl(g, base + 8);
        float gg = __shfl(g, base + 16);
        float go = __shfl(g, base + 24);
        float ii = sigm(gi), ff = sigm(gf), gt = ftanh(gg), oo = sigm(go);
        float c = ff * cst + ii * gt;
        cst = c;
        float h = oo * ftanh(c);

        // ---- publish: tag+payload in ONE 64-bit relaxed agent atomic,
        //      per-wave IMMEDIATE (no extra barrier). Mirror: write-through.
        {
            float hodd = __shfl(h, 32);                  // lane0 <- lane32's unit
            if (lane == 0) {
                unsigned pk = (unsigned)f2bf(h) | ((unsigned)f2bf(hodd) << 16);
                u64 sv = (((u64)(unsigned)(t + 1)) << 32) | (u64)pk;
                __hip_atomic_store(&myslots[(size_t)((t + 1) & 1) * 384 + pubslot],
                                   sv, __ATOMIC_RELAXED, __HIP_MEMORY_SCOPE_AGENT);
                __hip_atomic_store(
                    &((unsigned*)(hseq + (size_t)(t + 1) * H_DIM))[pubslot],
                    pk, __ATOMIC_RELAXED, __HIP_MEMORY_SCOPE_AGENT);
            }
        }
        // no trailing barrier: next step stages into the other LDS buffer,
        // and all reads of this buffer completed before the barrier above.
    }
}

// ---------------------------------------------------------------------------
// feats[s][j] = [hf[s], hb[s]] . w_tag[j] + b_tag[j]; one wave per s.
// ---------------------------------------------------------------------------
__global__ __launch_bounds__(256) void feats_kernel(const u16* __restrict__ hfseq,
                                                    const u16* __restrict__ hbseq,
                                                    const void* w_tag, const void* b_tag,
                                                    float* __restrict__ feats) {
    const int isbf = g_isbf16;
    const int wave = threadIdx.x >> 6, lane = threadIdx.x & 63;
    const int s = blockIdx.x * 4 + wave;
    if (s >= S_LEN) return;
    const u16* hf = hfseq + (size_t)(s + 1) * H_DIM;
    const u16* hb = hbseq + (size_t)(S_LEN - s) * H_DIM;
    float hv[12], hbv[12];
    #pragma unroll
    for (int i = 0; i < 12; ++i) {
        hv[i]  = bf2f(hf[lane + 64 * i]);
        hbv[i] = bf2f(hb[lane + 64 * i]);
    }
    float myf = 0.f;
    for (int j = 0; j < NTAG; ++j) {
        const size_t wr = (size_t)j * (2 * H_DIM);
        float d = 0.f;
        #pragma unroll
        for (int i = 0; i < 12; ++i)
            d += hv[i] * getv(w_tag, wr + lane + 64 * i, isbf)
               + hbv[i] * getv(w_tag, wr + H_DIM + lane + 64 * i, isbf);
        #pragma unroll
        for (int m = 1; m < 64; m <<= 1) d += __shfl_xor(d, m);
        if (lane == j) myf = d + getv(b_tag, j, isbf);
    }
    if (lane < NTAG) feats[(size_t)s * NTAG + lane] = myf;
}

// ---------------------------------------------------------------------------
// CRF parallel scan (log-semiring 7x7 product is associative).
// ---------------------------------------------------------------------------
__global__ void crf_chunks(const void* trans,
                           const float* __restrict__ feats,
                           float* __restrict__ cmats) {
    const int isbf = g_isbf16;
    const int c = blockIdx.x;
    const int lane = threadIdx.x;
    const bool act = lane < 49;
    const int i = act ? (lane / 7) : 0;
    const int j = lane % 7;
    float tc[7];
    #pragma unroll
    for (int k = 0; k < 7; ++k) tc[k] = getv(trans, k * 7 + j, isbf);
    float R = (act && (lane / 7) == j) ? 0.f : -1e30f;
    int s0 = 1 + c * 64;
    int s1 = s0 + 64; if (s1 > S_LEN) s1 = S_LEN;
    for (int t = s0; t < s1; ++t) {
        float fj = feats[t * NTAG + j];
        float r[7];
        #pragma unroll
        for (int k = 0; k < 7; ++k) r[k] = __shfl(R, i * 7 + k) + tc[k];
        float m = r[0];
        #pragma unroll
        for (int k = 1; k < 7; ++k) m = fmaxf(m, r[k]);
        float sum = 0.f;
        #pragma unroll
        for (int k = 0; k < 7; ++k) sum += __expf(r[k] - m);
        R = m + __logf(sum) + fj;
    }
    if (act) cmats[c * 49 + lane] = R;
}

__global__ void crf_final(const void* start_t, const void* end_t,
                          const float* __restrict__ feats,
                          const float* __restrict__ cmats,
                          void* __restrict__ out) {
    const int isbf = g_isbf16;
    const int lane = threadIdx.x;
    const int j = (lane < 7) ? lane : 0;
    float alpha = (lane < 7) ? (getv(start_t, lane, isbf) + feats[lane]) : -1e30f;
    for (int c = 0; c < NCHUNK; ++c) {
        float r[7];
        #pragma unroll
        for (int i = 0; i < 7; ++i)
            r[i] = __shfl(alpha, i) + cmats[c * 49 + i * 7 + j];
        float m = r[0];
        #pragma unroll
        for (int i = 1; i < 7; ++i) m = fmaxf(m, r[i]);
        float sum = 0.f;
        #pragma unroll
        for (int i = 0; i < 7; ++i) sum += __expf(r[i] - m);
        float na = m + __logf(sum);
        alpha = (lane < 7) ? na : -1e30f;
    }
    float v = (lane < 7) ? (alpha + getv(end_t, lane, isbf)) : -1e30f;
    float m = v;
    #pragma unroll
    for (int d = 1; d < 8; d <<= 1) m = fmaxf(m, __shfl_xor(m, d));
    float s = __expf(v - m);
    #pragma unroll
    for (int d = 1; d < 8; d <<= 1) s += __shfl_xor(s, d);
    if (lane == 0) {
        float r = m + __logf(s);
        if (isbf) ((u16*)out)[0] = f2bf(r);
        else      ((float*)out)[0] = r;
    }
}

// ---------------------------------------------------------------------------
extern "C" void kernel_launch(void* const* d_in, const int* in_sizes, int n_in,
                              void* d_out, int out_size, void* d_ws, size_t ws_size,
                              hipStream_t stream) {
    const void* sentence = d_in[0];      // (8192, 1, 100)
    const void* w_ih_f   = d_in[1];      // (3072, 100)
    const void* w_hh_f   = d_in[2];      // (3072, 768)
    const void* b_ih_f   = d_in[3];
    const void* b_hh_f   = d_in[4];
    const void* w_ih_b   = d_in[5];
    const void* w_hh_b   = d_in[6];
    const void* b_ih_b   = d_in[7];
    const void* b_hh_b   = d_in[8];
    const void* h0       = d_in[9];      // (2,1,768)
    const void* c0       = d_in[10];
    const void* w_tag    = d_in[11];     // (7, 1536)
    const void* b_tag    = d_in[12];
    const void* trans    = d_in[13];
    const void* start_t  = d_in[14];
    const void* end_t    = d_in[15];
    (void)in_sizes; (void)n_in; (void)out_size; (void)ws_size;

    // ---- d_ws scratch: ~25.3 MB, fully rewritten each call ----
    char* ws = (char*)d_ws;
    size_t o = 0;
    auto take = [&](size_t bytes) -> char* {
        char* p = ws + o;
        o += (bytes + 255) & ~(size_t)255;
        return p;
    };
    u16*   hfseq  = (u16*)take((size_t)(S_LEN + 1) * H_DIM * 2);
    u16*   hbseq  = (u16*)take((size_t)(S_LEN + 1) * H_DIM * 2);
    float* cstate = (float*)take((size_t)2 * H_DIM * 4);
    float* biasv  = (float*)take((size_t)2 * G4 * 4);
    float* featsb = (float*)take((size_t)S_LEN * NTAG * 4);
    float* cmats  = (float*)take((size_t)NCHUNK * 49 * 4);
    u64*   slots  = (u64*)take((size_t)2 * 2 * 384 * 8);   // [dir][buf][384]
    int*   bail   = (int*)take((size_t)256 * 4);

    detect<<<1, 128, 0, stream>>>(sentence);
    prep<<<12, 256, 0, stream>>>(b_ih_f, b_hh_f, b_ih_b, b_hh_b, h0, c0,
                                 cstate, biasv, slots);
    (void)hipMemsetAsync(bail, 0, 4, stream);

    lstm_persist<<<2 * NBLK, 256, 0, stream>>>(sentence,
                                               w_ih_f, w_hh_f, w_ih_b, w_hh_b,
                                               hfseq, hbseq, cstate, biasv,
                                               slots, bail);

    feats_kernel<<<S_LEN / 4, 256, 0, stream>>>(hfseq, hbseq, w_tag, b_tag, featsb);
    crf_chunks<<<NCHUNK, 64, 0, stream>>>(trans, featsb, cmats);
    crf_final<<<1, 64, 0, stream>>>(start_t, end_t, featsb, cmats, d_out);
}

// Round 8
// 15178.413 us; speedup vs baseline: 1.1441x; 1.0543x over previous
//
#include <hip/hip_runtime.h>
#include <stdint.h>

#define S_LEN 8192
#define E_DIM 100
#define H_DIM 768
#define NTAG 7
#define G4 3072            // 4*H
#define NBLK 96            // blocks per direction
#define NCHUNK 128
#define POLL_LIMIT 150000
#define NREP 4             // slot-array replicas (MALL contention spreading)
#define REPSTRIDE 1536     // u64 per replica: 2 dir x 2 buf x 384

typedef unsigned short u16;
typedef unsigned long long u64;
typedef __attribute__((ext_vector_type(4))) float f4v;

// input dtype flag (written by detect every call)
__device__ int g_isbf16;

__device__ __forceinline__ u16 f2bf(float f) {
    union { float f; unsigned u; } v; v.f = f;
    unsigned b = v.u;
    unsigned r = (b + 0x7FFFu + ((b >> 16) & 1u)) >> 16;   // RN
    return (u16)r;
}
__device__ __forceinline__ float bf2f(u16 u) {
    union { unsigned u; float f; } v; v.u = ((unsigned)u) << 16;
    return v.f;
}
__device__ __forceinline__ float getv(const void* p, size_t i, int isbf) {
    return isbf ? bf2f(((const u16*)p)[i]) : ((const float*)p)[i];
}
// fast transcendentals on the serial gate chain: v_exp + v_rcp.
__device__ __forceinline__ float sigm(float x) {
    return __builtin_amdgcn_rcpf(1.0f + __expf(-x));
}
__device__ __forceinline__ float ftanh(float x) {
    return 2.0f * __builtin_amdgcn_rcpf(1.0f + __expf(-2.0f * x)) - 1.0f;
}

// ---------------------------------------------------------------------------
// Dtype probe (256 B read, safe under either dtype).
// ---------------------------------------------------------------------------
__global__ void detect(const void* x) {
    __shared__ int cnt;
    if (threadIdx.x == 0) cnt = 0;
    __syncthreads();
    unsigned v = ((const u16*)x)[2 * threadIdx.x];
    int e = (v >> 7) & 0xFF;
    if (e >= 110 && e <= 132) atomicAdd(&cnt, 1);
    __syncthreads();
    if (threadIdx.x == 0) g_isbf16 = (cnt >= 100) ? 1 : 0;
}

// ---------------------------------------------------------------------------
// Prep: fold biases, seed c0, seed self-tagged h slots (ALL replicas).
// slots layout: [rep][dir][buf][384] u64 = (tag<<32) | (bf16 pair).
//   buf0 seeded with tag 0 + h0 payload; buf1 seeded with invalid tag
//   (kills stale tags from a previous invocation of this workspace).
// ---------------------------------------------------------------------------
__global__ void prep(const void* bihf, const void* bhhf,
                     const void* bihb, const void* bhhb,
                     const void* h0, const void* c0,
                     float* __restrict__ cst, float* __restrict__ bias,
                     u64* __restrict__ slots) {
    const int isbf = g_isbf16;
    int i = blockIdx.x * blockDim.x + threadIdx.x;   // 0..3071
    if (i < G4) {
        bias[i]      = getv(bihf, i, isbf) + getv(bhhf, i, isbf);
        bias[G4 + i] = getv(bihb, i, isbf) + getv(bhhb, i, isbf);
    }
    if (i < 2 * H_DIM) cst[i] = getv(c0, i, isbf);
    if (i < 384) {
        unsigned pf = (unsigned)f2bf(getv(h0, 2 * i, isbf))
                    | ((unsigned)f2bf(getv(h0, 2 * i + 1, isbf)) << 16);
        unsigned pb = (unsigned)f2bf(getv(h0, H_DIM + 2 * i, isbf))
                    | ((unsigned)f2bf(getv(h0, H_DIM + 2 * i + 1, isbf)) << 16);
        #pragma unroll
        for (int r = 0; r < NREP; ++r) {
            u64* rb = slots + (size_t)r * REPSTRIDE;
            rb[i]        = (u64)pf;                    // fwd buf0, tag 0
            rb[768 + i]  = (u64)pb;                    // bwd buf0, tag 0
            rb[384 + i]  = 0xFFFFFFFF00000000ull;      // fwd buf1, invalid tag
            rb[1152 + i] = 0xFFFFFFFF00000000ull;      // bwd buf1, invalid tag
        }
    }
}

// staggered-poll asm helpers (R5-verified). Poll loads MUST carry sc0 sc1
// (coherent-scope read, same point __hip_atomic_load(AGENT) uses).
#define PISSUE(A, B)                                                     \
    asm volatile("global_load_dwordx2 %0, %2, off sc0 sc1\n\t"           \
                 "global_load_dwordx2 %1, %3, off sc0 sc1"               \
                 : "=&v"(A), "=&v"(B) : "v"(pa), "v"(pb) : "memory")
#define PWAIT2(A, B)                                                     \
    asm volatile("s_waitcnt vmcnt(2)" : "+v"(A), "+v"(B))
#define PDRAIN4(A, B, C, D)                                              \
    asm volatile("s_waitcnt vmcnt(0)"                                    \
                 : "+v"(A), "+v"(B), "+v"(C), "+v"(D))

// ---------------------------------------------------------------------------
// Persistent bidirectional LSTM. 192 blocks (96/dir), 256 thr: 32 gate rows
// x 8 col-segments (R5 decomposition, verified best: 15.86 ms). Cross-block
// h exchange via SELF-TAGGED 64-bit slots; staggered 2-deep coherent poll;
// per-wave immediate publish; ONE barrier per step. R8 change: the slot
// array is REPLICATED 4x (12 KB apart -> distinct channels). Publishers
// store to all 4 replicas (pipelined, ~15 cy extra issue); each consumer
// block polls replica blk&3 only -> readers-per-MALL-line drop 96 -> 24,
// attacking queueing at the coherent point. Protocol/induction unchanged.
// ---------------------------------------------------------------------------
__global__ __launch_bounds__(256, 1) void lstm_persist(
        const void* x,
        const void* wihf, const void* whhf,
        const void* wihb, const void* whhb,
        u16* __restrict__ hfseq, u16* __restrict__ hbseq,
        float* __restrict__ cstate, const float* __restrict__ biasv,
        u64* __restrict__ slots, int* __restrict__ bail) {
    const int isbf = g_isbf16;
    const int bid = blockIdx.x;
    const int dir = (bid >= NBLK) ? 1 : 0;
    const int blk = bid - dir * NBLK;
    const int tid = threadIdx.x;
    const int wave = tid >> 6, lane = tid & 63;
    const int seg = tid & 7;            // col segment
    const int row = tid >> 3;           // 0..31 local gate rows
    const int gamma = row & 3;          // gate: 0=i 1=f 2=g 3=o
    const int uloc = row >> 2;          // 0..7
    const int u = blk * 8 + uloc;
    const size_t grow = (size_t)(gamma * H_DIM + u);       // row in (3072, .)
    u16* hseq = dir ? hbseq : hfseq;
    // poll replica: blk&3 spreads consumers across the 4 replicas
    u64* myslots = slots + (size_t)(blk & 3) * REPSTRIDE + (size_t)dir * 768;
    // publish bases: all replicas
    u64* pubbase = slots + (size_t)dir * 768;
    const void* Wih = dir ? wihb : wihf;
    const void* Whh = dir ? whhb : whhf;

    __shared__ float sh[1600];          // 2 x 800: h_t fp32, (k/96)*100 + k%96

    // ---- preload weights into registers (one-time) ----
    float whh[96], wih[13];
    if (isbf) {
        const unsigned* p = (const unsigned*)((const u16*)Whh + grow * H_DIM + seg * 96);
        #pragma unroll
        for (int i = 0; i < 48; ++i) {
            unsigned q = p[i];
            whh[2 * i] = bf2f((u16)q); whh[2 * i + 1] = bf2f((u16)(q >> 16));
        }
        const unsigned* px = (const unsigned*)((const u16*)Wih + grow * E_DIM + seg * 12);
        #pragma unroll
        for (int i = 0; i < 6; ++i) {
            unsigned q = px[i];
            wih[2 * i] = bf2f((u16)q); wih[2 * i + 1] = bf2f((u16)(q >> 16));
        }
        wih[12] = (seg < 4) ? bf2f(((const u16*)Wih)[grow * E_DIM + 96 + seg]) : 0.f;
    } else {
        const float* p = (const float*)Whh + grow * H_DIM + seg * 96;
        #pragma unroll
        for (int i = 0; i < 96; ++i) whh[i] = p[i];
        const float* px = (const float*)Wih + grow * E_DIM + seg * 12;
        #pragma unroll
        for (int i = 0; i < 12; ++i) wih[i] = px[i];
        wih[12] = (seg < 4) ? ((const float*)Wih)[grow * E_DIM + 96 + seg] : 0.f;
    }
    const float bias_r = biasv[dir * G4 + grow];
    const int uhalf = blk * 8 + wave * 2 + (lane >> 5);    // unit of this half-wave
    float cst = cstate[dir * H_DIM + uhalf];

    // ---- chunked slot assignment (R5): wave w polls slots [96w, 96w+96) ----
    const int sA = wave * 96 + lane;
    const int sB = (lane < 32) ? (wave * 96 + 64 + lane) : sA;
    // LDS staging offsets (layout (k/96)*100 + k%96), k = 2*slot
    const int kA = 2 * sA, kB = 2 * sB;
    const int oA = (kA / 96) * 100 + kA % 96;
    const int oB = (kB / 96) * 100 + kB % 96;
    const int pubslot = blk * 4 + wave;     // slot this wave publishes

    // ---- x-row register pipeline ----
    float    xf[13];        // fp32 path
    unsigned xu[6];         // bf16 path (96 cols)
    u16      xt16 = 0;      // bf16 tail col
    auto load_x = [&](int t) {
        const int sx = dir ? (S_LEN - 1 - t) : t;
        if (isbf) {
            const unsigned* xr = (const unsigned*)((const u16*)x + (size_t)sx * E_DIM + seg * 12);
            #pragma unroll
            for (int i = 0; i < 6; ++i) xu[i] = xr[i];
            if (seg < 4) xt16 = ((const u16*)x)[(size_t)sx * E_DIM + 96 + seg];
        } else {
            const float* xr = (const float*)x + (size_t)sx * E_DIM + seg * 12;
            #pragma unroll
            for (int i = 0; i < 12; ++i) xf[i] = xr[i];
            xf[12] = (seg < 4) ? ((const float*)x)[(size_t)sx * E_DIM + 96 + seg] : 0.f;
        }
    };
    auto fma_x = [&]() -> float {
        float ax = 0.f;
        if (isbf) {
            #pragma unroll
            for (int i = 0; i < 6; ++i) {
                unsigned q = xu[i];
                ax += wih[2 * i] * bf2f((u16)q) + wih[2 * i + 1] * bf2f((u16)(q >> 16));
            }
            if (seg < 4) ax += wih[12] * bf2f(xt16);
        } else {
            #pragma unroll
            for (int i = 0; i < 12; ++i) ax += wih[i] * xf[i];
            ax += wih[12] * xf[12];     // xf[12]=0 when seg>=4
        }
        return ax;
    };

    load_x(0);   // prologue

    for (int t = 0; t < S_LEN; ++t) {
        // ---- x-projection: pure FMAs on prefetched registers ----
        float ax = fma_x();

        // ---- staggered 2-deep poll of self-tagged h_t slots (R5) ----
        u64 va = 0, vb = 0;
        {
            const u64* buf = myslots + (size_t)(t & 1) * 384;
            const u64* pa = buf + sA;
            const u64* pb = buf + sB;
            const unsigned tgt = (unsigned)t;
            u64 a0p, b0p, a1p, b1p;
            int polls = 0;
            bool found = false;
            asm volatile("s_waitcnt vmcnt(0)" ::: "memory");
            for (;;) {
                PISSUE(a0p, b0p);
                for (int it = 0; it < 32; ++it) {
                    PISSUE(a1p, b1p);
                    PWAIT2(a0p, b0p);
                    if (__all(((unsigned)(a0p >> 32) == tgt) &
                              ((unsigned)(b0p >> 32) == tgt))) {
                        va = a0p; vb = b0p; found = true; break;
                    }
                    PISSUE(a0p, b0p);
                    PWAIT2(a1p, b1p);
                    if (__all(((unsigned)(a1p >> 32) == tgt) &
                              ((unsigned)(b1p >> 32) == tgt))) {
                        va = a1p; vb = b1p; found = true; break;
                    }
                }
                PDRAIN4(a0p, b0p, a1p, b1p);
                if (found) break;
                u64 f0 = __hip_atomic_load(&buf[sA], __ATOMIC_RELAXED,
                                           __HIP_MEMORY_SCOPE_AGENT);
                u64 f1 = __hip_atomic_load(&buf[sB], __ATOMIC_RELAXED,
                                           __HIP_MEMORY_SCOPE_AGENT);
                if (__all(((unsigned)(f0 >> 32) == tgt) &
                          ((unsigned)(f1 >> 32) == tgt))) {
                    va = f0; vb = f1; break;
                }
                polls += 64;
                if (__hip_atomic_load(bail, __ATOMIC_RELAXED,
                                      __HIP_MEMORY_SCOPE_AGENT)) {
                    va = f0; vb = f1; break;
                }
                if (polls > POLL_LIMIT) {
                    __hip_atomic_store(bail, 1, __ATOMIC_RELAXED,
                                       __HIP_MEMORY_SCOPE_AGENT);
                    va = f0; vb = f1; break;
                }
                __builtin_amdgcn_s_sleep(2);
            }

            // ---- unpack payload -> LDS (double-buffered) ----
            float* shb = sh + (t & 1) * 800;
            unsigned p0 = (unsigned)va;
            shb[oA]     = bf2f((u16)p0);
            shb[oA + 1] = bf2f((u16)(p0 >> 16));
            if (lane < 32) {
                unsigned p1 = (unsigned)vb;
                shb[oB]     = bf2f((u16)p1);
                shb[oB + 1] = bf2f((u16)(p1 >> 16));
            }
        }
        __syncthreads();   // single barrier/step: staging visible block-wide

        // ---- issue x-row loads for t+1 (latency hidden under h-proj) ----
        load_x((t + 1 < S_LEN) ? (t + 1) : t);

        // ---- h-projection: 96 FMA from LDS ----
        const float* hs = sh + (t & 1) * 800 + seg * 100;
        float a0 = 0.f, a1 = 0.f, a2 = 0.f, a3 = 0.f;
        #pragma unroll
        for (int i = 0; i < 24; ++i) {
            f4v hv = *(const f4v*)(hs + 4 * i);
            a0 += whh[4 * i]     * hv.x;
            a1 += whh[4 * i + 1] * hv.y;
            a2 += whh[4 * i + 2] * hv.z;
            a3 += whh[4 * i + 3] * hv.w;
        }
        float acc = ax + (a0 + a1) + (a2 + a3);
        acc += __shfl_xor(acc, 1);
        acc += __shfl_xor(acc, 2);
        acc += __shfl_xor(acc, 4);       // 8-lane row sum
        float g = acc + bias_r;

        const int base = lane & 32;      // 4 gates of this half-wave's unit
        float gi = __shfl(g, base + 0);
        float gf = __shfl(g, base + 8);
        float gg = __shfl(g, base + 16);
        float go = __shfl(g, base + 24);
        float ii = sigm(gi), ff = sigm(gf), gt = ftanh(gg), oo = sigm(go);
        float c = ff * cst + ii * gt;
        cst = c;
        float h = oo * ftanh(c);

        // ---- publish: tag+payload, one 8B relaxed agent store PER REPLICA,
        //      per-wave IMMEDIATE (no extra barrier). Mirror: write-through.
        {
            float hodd = __shfl(h, 32);                  // lane0 <- lane32's unit
            if (lane == 0) {
                unsigned pk = (unsigned)f2bf(h) | ((unsigned)f2bf(hodd) << 16);
                u64 sv = (((u64)(unsigned)(t + 1)) << 32) | (u64)pk;
                u64* dst = pubbase + (size_t)((t + 1) & 1) * 384 + pubslot;
                #pragma unroll
                for (int r = 0; r < NREP; ++r)
                    __hip_atomic_store(dst + (size_t)r * REPSTRIDE, sv,
                                       __ATOMIC_RELAXED, __HIP_MEMORY_SCOPE_AGENT);
                __hip_atomic_store(
                    &((unsigned*)(hseq + (size_t)(t + 1) * H_DIM))[pubslot],
                    pk, __ATOMIC_RELAXED, __HIP_MEMORY_SCOPE_AGENT);
            }
        }
        // no trailing barrier: next step stages into the other LDS buffer,
        // and all reads of this buffer completed before the barrier above.
    }
}

// ---------------------------------------------------------------------------
// feats[s][j] = [hf[s], hb[s]] . w_tag[j] + b_tag[j]; one wave per s.
// ---------------------------------------------------------------------------
__global__ __launch_bounds__(256) void feats_kernel(const u16* __restrict__ hfseq,
                                                    const u16* __restrict__ hbseq,
                                                    const void* w_tag, const void* b_tag,
                                                    float* __restrict__ feats) {
    const int isbf = g_isbf16;
    const int wave = threadIdx.x >> 6, lane = threadIdx.x & 63;
    const int s = blockIdx.x * 4 + wave;
    if (s >= S_LEN) return;
    const u16* hf = hfseq + (size_t)(s + 1) * H_DIM;
    const u16* hb = hbseq + (size_t)(S_LEN - s) * H_DIM;
    float hv[12], hbv[12];
    #pragma unroll
    for (int i = 0; i < 12; ++i) {
        hv[i]  = bf2f(hf[lane + 64 * i]);
        hbv[i] = bf2f(hb[lane + 64 * i]);
    }
    float myf = 0.f;
    for (int j = 0; j < NTAG; ++j) {
        const size_t wr = (size_t)j * (2 * H_DIM);
        float d = 0.f;
        #pragma unroll
        for (int i = 0; i < 12; ++i)
            d += hv[i] * getv(w_tag, wr + lane + 64 * i, isbf)
               + hbv[i] * getv(w_tag, wr + H_DIM + lane + 64 * i, isbf);
        #pragma unroll
        for (int m = 1; m < 64; m <<= 1) d += __shfl_xor(d, m);
        if (lane == j) myf = d + getv(b_tag, j, isbf);
    }
    if (lane < NTAG) feats[(size_t)s * NTAG + lane] = myf;
}

// ---------------------------------------------------------------------------
// CRF parallel scan (log-semiring 7x7 product is associative).
// ---------------------------------------------------------------------------
__global__ void crf_chunks(const void* trans,
                           const float* __restrict__ feats,
                           float* __restrict__ cmats) {
    const int isbf = g_isbf16;
    const int c = blockIdx.x;
    const int lane = threadIdx.x;
    const bool act = lane < 49;
    const int i = act ? (lane / 7) : 0;
    const int j = lane % 7;
    float tc[7];
    #pragma unroll
    for (int k = 0; k < 7; ++k) tc[k] = getv(trans, k * 7 + j, isbf);
    float R = (act && (lane / 7) == j) ? 0.f : -1e30f;
    int s0 = 1 + c * 64;
    int s1 = s0 + 64; if (s1 > S_LEN) s1 = S_LEN;
    for (int t = s0; t < s1; ++t) {
        float fj = feats[t * NTAG + j];
        float r[7];
        #pragma unroll
        for (int k = 0; k < 7; ++k) r[k] = __shfl(R, i * 7 + k) + tc[k];
        float m = r[0];
        #pragma unroll
        for (int k = 1; k < 7; ++k) m = fmaxf(m, r[k]);
        float sum = 0.f;
        #pragma unroll
        for (int k = 0; k < 7; ++k) sum += __expf(r[k] - m);
        R = m + __logf(sum) + fj;
    }
    if (act) cmats[c * 49 + lane] = R;
}

__global__ void crf_final(const void* start_t, const void* end_t,
                          const float* __restrict__ feats,
                          const float* __restrict__ cmats,
                          void* __restrict__ out) {
    const int isbf = g_isbf16;
    const int lane = threadIdx.x;
    const int j = (lane < 7) ? lane : 0;
    float alpha = (lane < 7) ? (getv(start_t, lane, isbf) + feats[lane]) : -1e30f;
    for (int c = 0; c < NCHUNK; ++c) {
        float r[7];
        #pragma unroll
        for (int i = 0; i < 7; ++i)
            r[i] = __shfl(alpha, i) + cmats[c * 49 + i * 7 + j];
        float m = r[0];
        #pragma unroll
        for (int i = 1; i < 7; ++i) m = fmaxf(m, r[i]);
        float sum = 0.f;
        #pragma unroll
        for (int i = 0; i < 7; ++i) sum += __expf(r[i] - m);
        float na = m + __logf(sum);
        alpha = (lane < 7) ? na : -1e30f;
    }
    float v = (lane < 7) ? (alpha + getv(end_t, lane, isbf)) : -1e30f;
    float m = v;
    #pragma unroll
    for (int d = 1; d < 8; d <<= 1) m = fmaxf(m, __shfl_xor(m, d));
    float s = __expf(v - m);
    #pragma unroll
    for (int d = 1; d < 8; d <<= 1) s += __shfl_xor(s, d);
    if (lane == 0) {
        float r = m + __logf(s);
        if (isbf) ((u16*)out)[0] = f2bf(r);
        else      ((float*)out)[0] = r;
    }
}

// ---------------------------------------------------------------------------
extern "C" void kernel_launch(void* const* d_in, const int* in_sizes, int n_in,
                              void* d_out, int out_size, void* d_ws, size_t ws_size,
                              hipStream_t stream) {
    const void* sentence = d_in[0];      // (8192, 1, 100)
    const void* w_ih_f   = d_in[1];      // (3072, 100)
    const void* w_hh_f   = d_in[2];      // (3072, 768)
    const void* b_ih_f   = d_in[3];
    const void* b_hh_f   = d_in[4];
    const void* w_ih_b   = d_in[5];
    const void* w_hh_b   = d_in[6];
    const void* b_ih_b   = d_in[7];
    const void* b_hh_b   = d_in[8];
    const void* h0       = d_in[9];      // (2,1,768)
    const void* c0       = d_in[10];
    const void* w_tag    = d_in[11];     // (7, 1536)
    const void* b_tag    = d_in[12];
    const void* trans    = d_in[13];
    const void* start_t  = d_in[14];
    const void* end_t    = d_in[15];
    (void)in_sizes; (void)n_in; (void)out_size; (void)ws_size;

    // ---- d_ws scratch: ~25.4 MB, fully rewritten each call ----
    char* ws = (char*)d_ws;
    size_t o = 0;
    auto take = [&](size_t bytes) -> char* {
        char* p = ws + o;
        o += (bytes + 255) & ~(size_t)255;
        return p;
    };
    u16*   hfseq  = (u16*)take((size_t)(S_LEN + 1) * H_DIM * 2);
    u16*   hbseq  = (u16*)take((size_t)(S_LEN + 1) * H_DIM * 2);
    float* cstate = (float*)take((size_t)2 * H_DIM * 4);
    float* biasv  = (float*)take((size_t)2 * G4 * 4);
    float* featsb = (float*)take((size_t)S_LEN * NTAG * 4);
    float* cmats  = (float*)take((size_t)NCHUNK * 49 * 4);
    u64*   slots  = (u64*)take((size_t)NREP * REPSTRIDE * 8);  // [rep][dir][buf][384]
    int*   bail   = (int*)take((size_t)256 * 4);

    detect<<<1, 128, 0, stream>>>(sentence);
    prep<<<12, 256, 0, stream>>>(b_ih_f, b_hh_f, b_ih_b, b_hh_b, h0, c0,
                                 cstate, biasv, slots);
    (void)hipMemsetAsync(bail, 0, 4, stream);

    lstm_persist<<<2 * NBLK, 256, 0, stream>>>(sentence,
                                               w_ih_f, w_hh_f, w_ih_b, w_hh_b,
                                               hfseq, hbseq, cstate, biasv,
                                               slots, bail);

    feats_kernel<<<S_LEN / 4, 256, 0, stream>>>(hfseq, hbseq, w_tag, b_tag, featsb);
    crf_chunks<<<NCHUNK, 64, 0, stream>>>(trans, featsb, cmats);
    crf_final<<<1, 64, 0, stream>>>(start_t, end_t, featsb, cmats, d_out);
}

// Round 9
// 14820.012 us; speedup vs baseline: 1.1718x; 1.0242x over previous
//
#include <hip/hip_runtime.h>
#include <stdint.h>

#define S_LEN 8192
#define E_DIM 100
#define H_DIM 768
#define NTAG 7
#define G4 3072            // 4*H
#define NBLK 96            // blocks per direction
#define NCHUNK 128
#define POLL_LIMIT 150000
#define NREP 4             // slot-array replicas (MALL contention spreading)
#define REPSTRIDE 1536     // u64 per replica: 2 dir x 2 buf x 384

typedef unsigned short u16;
typedef unsigned long long u64;
typedef __attribute__((ext_vector_type(4))) float f4v;

// input dtype flag (written by detect every call)
__device__ int g_isbf16;

__device__ __forceinline__ u16 f2bf(float f) {
    union { float f; unsigned u; } v; v.f = f;
    unsigned b = v.u;
    unsigned r = (b + 0x7FFFu + ((b >> 16) & 1u)) >> 16;   // RN
    return (u16)r;
}
__device__ __forceinline__ float bf2f(u16 u) {
    union { unsigned u; float f; } v; v.u = ((unsigned)u) << 16;
    return v.f;
}
__device__ __forceinline__ float getv(const void* p, size_t i, int isbf) {
    return isbf ? bf2f(((const u16*)p)[i]) : ((const float*)p)[i];
}
// fast transcendentals on the serial gate chain: v_exp + v_rcp.
__device__ __forceinline__ float sigm(float x) {
    return __builtin_amdgcn_rcpf(1.0f + __expf(-x));
}
__device__ __forceinline__ float ftanh(float x) {
    return 2.0f * __builtin_amdgcn_rcpf(1.0f + __expf(-2.0f * x)) - 1.0f;
}

// ---------------------------------------------------------------------------
// Dtype probe (256 B read, safe under either dtype).
// ---------------------------------------------------------------------------
__global__ void detect(const void* x) {
    __shared__ int cnt;
    if (threadIdx.x == 0) cnt = 0;
    __syncthreads();
    unsigned v = ((const u16*)x)[2 * threadIdx.x];
    int e = (v >> 7) & 0xFF;
    if (e >= 110 && e <= 132) atomicAdd(&cnt, 1);
    __syncthreads();
    if (threadIdx.x == 0) g_isbf16 = (cnt >= 100) ? 1 : 0;
}

// ---------------------------------------------------------------------------
// Prep: fold biases, seed c0, seed self-tagged h slots (ALL replicas).
// slots layout: [rep][dir][buf][384] u64 = (tag<<32) | (bf16 pair).
// ---------------------------------------------------------------------------
__global__ void prep(const void* bihf, const void* bhhf,
                     const void* bihb, const void* bhhb,
                     const void* h0, const void* c0,
                     float* __restrict__ cst, float* __restrict__ bias,
                     u64* __restrict__ slots) {
    const int isbf = g_isbf16;
    int i = blockIdx.x * blockDim.x + threadIdx.x;   // 0..3071
    if (i < G4) {
        bias[i]      = getv(bihf, i, isbf) + getv(bhhf, i, isbf);
        bias[G4 + i] = getv(bihb, i, isbf) + getv(bhhb, i, isbf);
    }
    if (i < 2 * H_DIM) cst[i] = getv(c0, i, isbf);
    if (i < 384) {
        unsigned pf = (unsigned)f2bf(getv(h0, 2 * i, isbf))
                    | ((unsigned)f2bf(getv(h0, 2 * i + 1, isbf)) << 16);
        unsigned pb = (unsigned)f2bf(getv(h0, H_DIM + 2 * i, isbf))
                    | ((unsigned)f2bf(getv(h0, H_DIM + 2 * i + 1, isbf)) << 16);
        #pragma unroll
        for (int r = 0; r < NREP; ++r) {
            u64* rb = slots + (size_t)r * REPSTRIDE;
            rb[i]        = (u64)pf;                    // fwd buf0, tag 0
            rb[768 + i]  = (u64)pb;                    // bwd buf0, tag 0
            rb[384 + i]  = 0xFFFFFFFF00000000ull;      // fwd buf1, invalid tag
            rb[1152 + i] = 0xFFFFFFFF00000000ull;      // bwd buf1, invalid tag
        }
    }
}

// staggered-poll asm helpers (R5-verified). Poll loads MUST carry sc0 sc1
// (coherent-scope read, same point __hip_atomic_load(AGENT) uses).
#define PISSUE(A, B)                                                     \
    asm volatile("global_load_dwordx2 %0, %2, off sc0 sc1\n\t"           \
                 "global_load_dwordx2 %1, %3, off sc0 sc1"               \
                 : "=&v"(A), "=&v"(B) : "v"(pa), "v"(pb) : "memory")
#define PWAIT2(A, B)                                                     \
    asm volatile("s_waitcnt vmcnt(2)" : "+v"(A), "+v"(B))
#define PDRAIN4(A, B, C, D)                                              \
    asm volatile("s_waitcnt vmcnt(0)"                                    \
                 : "+v"(A), "+v"(B), "+v"(C), "+v"(D))

// ---------------------------------------------------------------------------
// Persistent bidirectional LSTM. 192 blocks (96/dir), 256 thr: 32 gate rows
// x 8 col-segments. Self-tagged 64-bit slot exchange, 4x-replicated slot
// array (R8, confirmed: -4.3%), per-wave immediate publish, ONE barrier
// per step. R9 change: TWO-PHASE poll to cut the global coherent-read
// request rate (~37 line-req/cy ~ 5.7 TB/s at the MALL was near service
// saturation). Coarse phase: 1-deep sample + readiness ballot, s_sleep(2)
// between samples (~4-5x lower rate) while <56/64 lanes ready. Fine phase:
// R5's staggered 2-deep sampler for sharp detection of the last few
// publishers. Per-wave tail cost <= one coarse quantum; global queueing
// drops for every load in the system.
// ---------------------------------------------------------------------------
__global__ __launch_bounds__(256, 1) void lstm_persist(
        const void* x,
        const void* wihf, const void* whhf,
        const void* wihb, const void* whhb,
        u16* __restrict__ hfseq, u16* __restrict__ hbseq,
        float* __restrict__ cstate, const float* __restrict__ biasv,
        u64* __restrict__ slots, int* __restrict__ bail) {
    const int isbf = g_isbf16;
    const int bid = blockIdx.x;
    const int dir = (bid >= NBLK) ? 1 : 0;
    const int blk = bid - dir * NBLK;
    const int tid = threadIdx.x;
    const int wave = tid >> 6, lane = tid & 63;
    const int seg = tid & 7;            // col segment
    const int row = tid >> 3;           // 0..31 local gate rows
    const int gamma = row & 3;          // gate: 0=i 1=f 2=g 3=o
    const int uloc = row >> 2;          // 0..7
    const int u = blk * 8 + uloc;
    const size_t grow = (size_t)(gamma * H_DIM + u);       // row in (3072, .)
    u16* hseq = dir ? hbseq : hfseq;
    // poll replica: blk&3 spreads consumers across the 4 replicas
    u64* myslots = slots + (size_t)(blk & 3) * REPSTRIDE + (size_t)dir * 768;
    // publish bases: all replicas
    u64* pubbase = slots + (size_t)dir * 768;
    const void* Wih = dir ? wihb : wihf;
    const void* Whh = dir ? whhb : whhf;

    __shared__ float sh[1600];          // 2 x 800: h_t fp32, (k/96)*100 + k%96

    // ---- preload weights into registers (one-time) ----
    float whh[96], wih[13];
    if (isbf) {
        const unsigned* p = (const unsigned*)((const u16*)Whh + grow * H_DIM + seg * 96);
        #pragma unroll
        for (int i = 0; i < 48; ++i) {
            unsigned q = p[i];
            whh[2 * i] = bf2f((u16)q); whh[2 * i + 1] = bf2f((u16)(q >> 16));
        }
        const unsigned* px = (const unsigned*)((const u16*)Wih + grow * E_DIM + seg * 12);
        #pragma unroll
        for (int i = 0; i < 6; ++i) {
            unsigned q = px[i];
            wih[2 * i] = bf2f((u16)q); wih[2 * i + 1] = bf2f((u16)(q >> 16));
        }
        wih[12] = (seg < 4) ? bf2f(((const u16*)Wih)[grow * E_DIM + 96 + seg]) : 0.f;
    } else {
        const float* p = (const float*)Whh + grow * H_DIM + seg * 96;
        #pragma unroll
        for (int i = 0; i < 96; ++i) whh[i] = p[i];
        const float* px = (const float*)Wih + grow * E_DIM + seg * 12;
        #pragma unroll
        for (int i = 0; i < 12; ++i) wih[i] = px[i];
        wih[12] = (seg < 4) ? ((const float*)Wih)[grow * E_DIM + 96 + seg] : 0.f;
    }
    const float bias_r = biasv[dir * G4 + grow];
    const int uhalf = blk * 8 + wave * 2 + (lane >> 5);    // unit of this half-wave
    float cst = cstate[dir * H_DIM + uhalf];

    // ---- chunked slot assignment (R5): wave w polls slots [96w, 96w+96) ----
    const int sA = wave * 96 + lane;
    const int sB = (lane < 32) ? (wave * 96 + 64 + lane) : sA;
    // LDS staging offsets (layout (k/96)*100 + k%96), k = 2*slot
    const int kA = 2 * sA, kB = 2 * sB;
    const int oA = (kA / 96) * 100 + kA % 96;
    const int oB = (kB / 96) * 100 + kB % 96;
    const int pubslot = blk * 4 + wave;     // slot this wave publishes

    // ---- x-row register pipeline ----
    float    xf[13];        // fp32 path
    unsigned xu[6];         // bf16 path (96 cols)
    u16      xt16 = 0;      // bf16 tail col
    auto load_x = [&](int t) {
        const int sx = dir ? (S_LEN - 1 - t) : t;
        if (isbf) {
            const unsigned* xr = (const unsigned*)((const u16*)x + (size_t)sx * E_DIM + seg * 12);
            #pragma unroll
            for (int i = 0; i < 6; ++i) xu[i] = xr[i];
            if (seg < 4) xt16 = ((const u16*)x)[(size_t)sx * E_DIM + 96 + seg];
        } else {
            const float* xr = (const float*)x + (size_t)sx * E_DIM + seg * 12;
            #pragma unroll
            for (int i = 0; i < 12; ++i) xf[i] = xr[i];
            xf[12] = (seg < 4) ? ((const float*)x)[(size_t)sx * E_DIM + 96 + seg] : 0.f;
        }
    };
    auto fma_x = [&]() -> float {
        float ax = 0.f;
        if (isbf) {
            #pragma unroll
            for (int i = 0; i < 6; ++i) {
                unsigned q = xu[i];
                ax += wih[2 * i] * bf2f((u16)q) + wih[2 * i + 1] * bf2f((u16)(q >> 16));
            }
            if (seg < 4) ax += wih[12] * bf2f(xt16);
        } else {
            #pragma unroll
            for (int i = 0; i < 12; ++i) ax += wih[i] * xf[i];
            ax += wih[12] * xf[12];     // xf[12]=0 when seg>=4
        }
        return ax;
    };

    load_x(0);   // prologue

    for (int t = 0; t < S_LEN; ++t) {
        // ---- x-projection: pure FMAs on prefetched registers ----
        float ax = fma_x();

        // ---- two-phase poll of self-tagged h_t slots ----
        u64 va = 0, vb = 0;
        {
            const u64* buf = myslots + (size_t)(t & 1) * 384;
            const u64* pa = buf + sA;
            const u64* pb = buf + sB;
            const unsigned tgt = (unsigned)t;
            const u64 pass = ((u64)tgt) << 32;   // auto-pass for lane>=32's sB
            int polls = 0;
            bool done = false, bailed = false;

            // ==== coarse phase: low-rate 1-deep sampling + readiness ballot ====
            for (;;) {
                u64 c0 = __hip_atomic_load(&buf[sA], __ATOMIC_RELAXED,
                                           __HIP_MEMORY_SCOPE_AGENT);
                u64 c1 = (lane < 32)
                       ? __hip_atomic_load(&buf[sB], __ATOMIC_RELAXED,
                                           __HIP_MEMORY_SCOPE_AGENT) : pass;
                bool ok = ((unsigned)(c0 >> 32) == tgt) &
                          ((unsigned)(c1 >> 32) == tgt);
                unsigned long long nb = __ballot(ok);
                if (nb == ~0ull) { va = c0; vb = c1; done = true; break; }
                if (__popcll(nb) >= 56) break;           // near-ready -> fine
                polls += 8;
                if ((polls & 63) == 0) {
                    if (__hip_atomic_load(bail, __ATOMIC_RELAXED,
                                          __HIP_MEMORY_SCOPE_AGENT)) {
                        va = c0; vb = c1; done = true; bailed = true; break;
                    }
                    if (polls > POLL_LIMIT) {
                        __hip_atomic_store(bail, 1, __ATOMIC_RELAXED,
                                           __HIP_MEMORY_SCOPE_AGENT);
                        va = c0; vb = c1; done = true; bailed = true; break;
                    }
                }
                __builtin_amdgcn_s_sleep(2);
            }
            (void)bailed;

            // ==== fine phase: staggered 2-deep sampler (R5-verified) ====
            if (!done) {
                u64 a0p, b0p, a1p, b1p;
                bool found = false;
                asm volatile("s_waitcnt vmcnt(0)" ::: "memory");
                for (;;) {
                    PISSUE(a0p, b0p);
                    for (int it = 0; it < 32; ++it) {
                        PISSUE(a1p, b1p);
                        PWAIT2(a0p, b0p);
                        if (__all(((unsigned)(a0p >> 32) == tgt) &
                                  ((unsigned)(b0p >> 32) == tgt))) {
                            va = a0p; vb = b0p; found = true; break;
                        }
                        PISSUE(a0p, b0p);
                        PWAIT2(a1p, b1p);
                        if (__all(((unsigned)(a1p >> 32) == tgt) &
                                  ((unsigned)(b1p >> 32) == tgt))) {
                            va = a1p; vb = b1p; found = true; break;
                        }
                    }
                    PDRAIN4(a0p, b0p, a1p, b1p);
                    if (found) break;
                    u64 f0 = __hip_atomic_load(&buf[sA], __ATOMIC_RELAXED,
                                               __HIP_MEMORY_SCOPE_AGENT);
                    u64 f1 = __hip_atomic_load(&buf[sB], __ATOMIC_RELAXED,
                                               __HIP_MEMORY_SCOPE_AGENT);
                    if (__all(((unsigned)(f0 >> 32) == tgt) &
                              ((unsigned)(f1 >> 32) == tgt))) {
                        va = f0; vb = f1; break;
                    }
                    polls += 64;
                    if (__hip_atomic_load(bail, __ATOMIC_RELAXED,
                                          __HIP_MEMORY_SCOPE_AGENT)) {
                        va = f0; vb = f1; break;
                    }
                    if (polls > POLL_LIMIT) {
                        __hip_atomic_store(bail, 1, __ATOMIC_RELAXED,
                                           __HIP_MEMORY_SCOPE_AGENT);
                        va = f0; vb = f1; break;
                    }
                    __builtin_amdgcn_s_sleep(2);
                }
            }

            // ---- unpack payload -> LDS (double-buffered) ----
            float* shb = sh + (t & 1) * 800;
            unsigned p0 = (unsigned)va;
            shb[oA]     = bf2f((u16)p0);
            shb[oA + 1] = bf2f((u16)(p0 >> 16));
            if (lane < 32) {
                unsigned p1 = (unsigned)vb;
                shb[oB]     = bf2f((u16)p1);
                shb[oB + 1] = bf2f((u16)(p1 >> 16));
            }
        }
        __syncthreads();   // single barrier/step: staging visible block-wide

        // ---- issue x-row loads for t+1 (latency hidden under h-proj) ----
        load_x((t + 1 < S_LEN) ? (t + 1) : t);

        // ---- h-projection: 96 FMA from LDS ----
        const float* hs = sh + (t & 1) * 800 + seg * 100;
        float a0 = 0.f, a1 = 0.f, a2 = 0.f, a3 = 0.f;
        #pragma unroll
        for (int i = 0; i < 24; ++i) {
            f4v hv = *(const f4v*)(hs + 4 * i);
            a0 += whh[4 * i]     * hv.x;
            a1 += whh[4 * i + 1] * hv.y;
            a2 += whh[4 * i + 2] * hv.z;
            a3 += whh[4 * i + 3] * hv.w;
        }
        float acc = ax + (a0 + a1) + (a2 + a3);
        acc += __shfl_xor(acc, 1);
        acc += __shfl_xor(acc, 2);
        acc += __shfl_xor(acc, 4);       // 8-lane row sum
        float g = acc + bias_r;

        const int base = lane & 32;      // 4 gates of this half-wave's unit
        float gi = __shfl(g, base + 0);
        float gf = __shfl(g, base + 8);
        float gg = __shfl(g, base + 16);
        float go = __shfl(g, base + 24);
        float ii = sigm(gi), ff = sigm(gf), gt = ftanh(gg), oo = sigm(go);
        float c = ff * cst + ii * gt;
        cst = c;
        float h = oo * ftanh(c);

        // ---- publish: tag+payload, one 8B relaxed agent store PER REPLICA,
        //      per-wave IMMEDIATE (no extra barrier). Mirror: write-through.
        {
            float hodd = __shfl(h, 32);                  // lane0 <- lane32's unit
            if (lane == 0) {
                unsigned pk = (unsigned)f2bf(h) | ((unsigned)f2bf(hodd) << 16);
                u64 sv = (((u64)(unsigned)(t + 1)) << 32) | (u64)pk;
                u64* dst = pubbase + (size_t)((t + 1) & 1) * 384 + pubslot;
                #pragma unroll
                for (int r = 0; r < NREP; ++r)
                    __hip_atomic_store(dst + (size_t)r * REPSTRIDE, sv,
                                       __ATOMIC_RELAXED, __HIP_MEMORY_SCOPE_AGENT);
                __hip_atomic_store(
                    &((unsigned*)(hseq + (size_t)(t + 1) * H_DIM))[pubslot],
                    pk, __ATOMIC_RELAXED, __HIP_MEMORY_SCOPE_AGENT);
            }
        }
        // no trailing barrier: next step stages into the other LDS buffer,
        // and all reads of this buffer completed before the barrier above.
    }
}

// ---------------------------------------------------------------------------
// feats[s][j] = [hf[s], hb[s]] . w_tag[j] + b_tag[j]; one wave per s.
// ---------------------------------------------------------------------------
__global__ __launch_bounds__(256) void feats_kernel(const u16* __restrict__ hfseq,
                                                    const u16* __restrict__ hbseq,
                                                    const void* w_tag, const void* b_tag,
                                                    float* __restrict__ feats) {
    const int isbf = g_isbf16;
    const int wave = threadIdx.x >> 6, lane = threadIdx.x & 63;
    const int s = blockIdx.x * 4 + wave;
    if (s >= S_LEN) return;
    const u16* hf = hfseq + (size_t)(s + 1) * H_DIM;
    const u16* hb = hbseq + (size_t)(S_LEN - s) * H_DIM;
    float hv[12], hbv[12];
    #pragma unroll
    for (int i = 0; i < 12; ++i) {
        hv[i]  = bf2f(hf[lane + 64 * i]);
        hbv[i] = bf2f(hb[lane + 64 * i]);
    }
    float myf = 0.f;
    for (int j = 0; j < NTAG; ++j) {
        const size_t wr = (size_t)j * (2 * H_DIM);
        float d = 0.f;
        #pragma unroll
        for (int i = 0; i < 12; ++i)
            d += hv[i] * getv(w_tag, wr + lane + 64 * i, isbf)
               + hbv[i] * getv(w_tag, wr + H_DIM + lane + 64 * i, isbf);
        #pragma unroll
        for (int m = 1; m < 64; m <<= 1) d += __shfl_xor(d, m);
        if (lane == j) myf = d + getv(b_tag, j, isbf);
    }
    if (lane < NTAG) feats[(size_t)s * NTAG + lane] = myf;
}

// ---------------------------------------------------------------------------
// CRF parallel scan (log-semiring 7x7 product is associative).
// ---------------------------------------------------------------------------
__global__ void crf_chunks(const void* trans,
                           const float* __restrict__ feats,
                           float* __restrict__ cmats) {
    const int isbf = g_isbf16;
    const int c = blockIdx.x;
    const int lane = threadIdx.x;
    const bool act = lane < 49;
    const int i = act ? (lane / 7) : 0;
    const int j = lane % 7;
    float tc[7];
    #pragma unroll
    for (int k = 0; k < 7; ++k) tc[k] = getv(trans, k * 7 + j, isbf);
    float R = (act && (lane / 7) == j) ? 0.f : -1e30f;
    int s0 = 1 + c * 64;
    int s1 = s0 + 64; if (s1 > S_LEN) s1 = S_LEN;
    for (int t = s0; t < s1; ++t) {
        float fj = feats[t * NTAG + j];
        float r[7];
        #pragma unroll
        for (int k = 0; k < 7; ++k) r[k] = __shfl(R, i * 7 + k) + tc[k];
        float m = r[0];
        #pragma unroll
        for (int k = 1; k < 7; ++k) m = fmaxf(m, r[k]);
        float sum = 0.f;
        #pragma unroll
        for (int k = 0; k < 7; ++k) sum += __expf(r[k] - m);
        R = m + __logf(sum) + fj;
    }
    if (act) cmats[c * 49 + lane] = R;
}

__global__ void crf_final(const void* start_t, const void* end_t,
                          const float* __restrict__ feats,
                          const float* __restrict__ cmats,
                          void* __restrict__ out) {
    const int isbf = g_isbf16;
    const int lane = threadIdx.x;
    const int j = (lane < 7) ? lane : 0;
    float alpha = (lane < 7) ? (getv(start_t, lane, isbf) + feats[lane]) : -1e30f;
    for (int c = 0; c < NCHUNK; ++c) {
        float r[7];
        #pragma unroll
        for (int i = 0; i < 7; ++i)
            r[i] = __shfl(alpha, i) + cmats[c * 49 + i * 7 + j];
        float m = r[0];
        #pragma unroll
        for (int i = 1; i < 7; ++i) m = fmaxf(m, r[i]);
        float sum = 0.f;
        #pragma unroll
        for (int i = 0; i < 7; ++i) sum += __expf(r[i] - m);
        float na = m + __logf(sum);
        alpha = (lane < 7) ? na : -1e30f;
    }
    float v = (lane < 7) ? (alpha + getv(end_t, lane, isbf)) : -1e30f;
    float m = v;
    #pragma unroll
    for (int d = 1; d < 8; d <<= 1) m = fmaxf(m, __shfl_xor(m, d));
    float s = __expf(v - m);
    #pragma unroll
    for (int d = 1; d < 8; d <<= 1) s += __shfl_xor(s, d);
    if (lane == 0) {
        float r = m + __logf(s);
        if (isbf) ((u16*)out)[0] = f2bf(r);
        else      ((float*)out)[0] = r;
    }
}

// ---------------------------------------------------------------------------
extern "C" void kernel_launch(void* const* d_in, const int* in_sizes, int n_in,
                              void* d_out, int out_size, void* d_ws, size_t ws_size,
                              hipStream_t stream) {
    const void* sentence = d_in[0];      // (8192, 1, 100)
    const void* w_ih_f   = d_in[1];      // (3072, 100)
    const void* w_hh_f   = d_in[2];      // (3072, 768)
    const void* b_ih_f   = d_in[3];
    const void* b_hh_f   = d_in[4];
    const void* w_ih_b   = d_in[5];
    const void* w_hh_b   = d_in[6];
    const void* b_ih_b   = d_in[7];
    const void* b_hh_b   = d_in[8];
    const void* h0       = d_in[9];      // (2,1,768)
    const void* c0       = d_in[10];
    const void* w_tag    = d_in[11];     // (7, 1536)
    const void* b_tag    = d_in[12];
    const void* trans    = d_in[13];
    const void* start_t  = d_in[14];
    const void* end_t    = d_in[15];
    (void)in_sizes; (void)n_in; (void)out_size; (void)ws_size;

    // ---- d_ws scratch: ~25.4 MB, fully rewritten each call ----
    char* ws = (char*)d_ws;
    size_t o = 0;
    auto take = [&](size_t bytes) -> char* {
        char* p = ws + o;
        o += (bytes + 255) & ~(size_t)255;
        return p;
    };
    u16*   hfseq  = (u16*)take((size_t)(S_LEN + 1) * H_DIM * 2);
    u16*   hbseq  = (u16*)take((size_t)(S_LEN + 1) * H_DIM * 2);
    float* cstate = (float*)take((size_t)2 * H_DIM * 4);
    float* biasv  = (float*)take((size_t)2 * G4 * 4);
    float* featsb = (float*)take((size_t)S_LEN * NTAG * 4);
    float* cmats  = (float*)take((size_t)NCHUNK * 49 * 4);
    u64*   slots  = (u64*)take((size_t)NREP * REPSTRIDE * 8);  // [rep][dir][buf][384]
    int*   bail   = (int*)take((size_t)256 * 4);

    detect<<<1, 128, 0, stream>>>(sentence);
    prep<<<12, 256, 0, stream>>>(b_ih_f, b_hh_f, b_ih_b, b_hh_b, h0, c0,
                                 cstate, biasv, slots);
    (void)hipMemsetAsync(bail, 0, 4, stream);

    lstm_persist<<<2 * NBLK, 256, 0, stream>>>(sentence,
                                               w_ih_f, w_hh_f, w_ih_b, w_hh_b,
                                               hfseq, hbseq, cstate, biasv,
                                               slots, bail);

    feats_kernel<<<S_LEN / 4, 256, 0, stream>>>(hfseq, hbseq, w_tag, b_tag, featsb);
    crf_chunks<<<NCHUNK, 64, 0, stream>>>(trans, featsb, cmats);
    crf_final<<<1, 64, 0, stream>>>(start_t, end_t, featsb, cmats, d_out);
}